// Round 2
// baseline (415.290 us; speedup 1.0000x reference)
//
#include <hip/hip_runtime.h>

typedef unsigned short u16;
typedef unsigned int u32;
typedef __attribute__((ext_vector_type(8))) short bf16x8;
typedef __attribute__((ext_vector_type(4))) float f32x4;

#define KDIM   512
#define NROWS  1024
#define NCLS   100000
#define CPAD   100096   // 782*128
#define NSTRIP 782
#define NMT    8        // 1024/128

#define COS_M_C   0.8775825618903728f
#define SIN_M_C   0.4794255386042030f
#define THRESH_C  (-0.8775825618903728f)
#define MM_C      0.2397127693021015f
#define S_C       64.0f

__device__ __forceinline__ u16 f2bf(float f) {
    u32 x = __float_as_uint(f);
    x += 0x7fffu + ((x >> 16) & 1u);   // RNE
    return (u16)(x >> 16);
}
__device__ __forceinline__ float bf2f(u16 u) {
    return __uint_as_float(((u32)u) << 16);
}

__device__ __forceinline__ void gld16(const void* g, void* l) {
    __builtin_amdgcn_global_load_lds(
        (const __attribute__((address_space(1))) void*)g,
        (__attribute__((address_space(3))) void*)l, 16, 0, 0);
}

// ---------------- kernel 1: row-normalize embeddings ----------------
__global__ __launch_bounds__(64)
void norm_emb_k(const float* __restrict__ emb, float* __restrict__ Af,
                u16* __restrict__ Aw) {
    const int i = blockIdx.x, l = threadIdx.x;
    const float* e = emb + i * KDIM;
    float4 v0 = *(const float4*)(e + l * 4);
    float4 v1 = *(const float4*)(e + 256 + l * 4);
    float s = v0.x*v0.x + v0.y*v0.y + v0.z*v0.z + v0.w*v0.w
            + v1.x*v1.x + v1.y*v1.y + v1.z*v1.z + v1.w*v1.w;
    #pragma unroll
    for (int o = 1; o < 64; o <<= 1) s += __shfl_xor(s, o);
    float inv = rsqrtf(s);
    float4 n0 = make_float4(v0.x*inv, v0.y*inv, v0.z*inv, v0.w*inv);
    float4 n1 = make_float4(v1.x*inv, v1.y*inv, v1.z*inv, v1.w*inv);
    *(float4*)(Af + i*KDIM + l*4)       = n0;
    *(float4*)(Af + i*KDIM + 256 + l*4) = n1;
    ushort4 p0 = { f2bf(n0.x), f2bf(n0.y), f2bf(n0.z), f2bf(n0.w) };
    ushort4 p1 = { f2bf(n1.x), f2bf(n1.y), f2bf(n1.z), f2bf(n1.w) };
    *(ushort4*)(Aw + i*KDIM + l*4)       = p0;
    *(ushort4*)(Aw + i*KDIM + 256 + l*4) = p1;
}

// ------- kernel 2: transpose+convert W [512][100000]f32 -> Bn bf16 in the
//         GEMM-LDS image layout [strip][kstep(16)][col(128)][k(32)],
//         plus per-column inverse norms -------
__global__ __launch_bounds__(128)
void transpose_norm_k(const float* __restrict__ Kg, u16* __restrict__ Bn,
                      float* __restrict__ kinv) {
    __shared__ float Ls[32 * 132];           // 32 k-rows x 128 cols, pad 132
    const int t  = threadIdx.x;
    const int jb = blockIdx.x * 128;
    const int j  = jb + t;
    u16* bstrip = Bn + (size_t)blockIdx.x * 65536;   // 16*128*32 u16
    float acc = 0.f;
    for (int kc = 0; kc < 16; ++kc) {        // chunks of 32 k
        #pragma unroll
        for (int it = 0; it < 8; ++it) {
            int fid  = it * 128 + t;
            int r    = fid >> 5;
            int c4   = (fid & 31) * 4;
            int gcol = jb + c4;
            float4 v;
            if (gcol + 3 < NCLS) {
                v = *(const float4*)(Kg + (kc*32 + r) * NCLS + gcol);
            } else {
                v.x = (gcol + 0 < NCLS) ? Kg[(kc*32 + r)*NCLS + gcol + 0] : 0.f;
                v.y = (gcol + 1 < NCLS) ? Kg[(kc*32 + r)*NCLS + gcol + 1] : 0.f;
                v.z = (gcol + 2 < NCLS) ? Kg[(kc*32 + r)*NCLS + gcol + 2] : 0.f;
                v.w = (gcol + 3 < NCLS) ? Kg[(kc*32 + r)*NCLS + gcol + 3] : 0.f;
            }
            *(float4*)(Ls + r * 132 + c4) = v;
        }
        __syncthreads();
        #pragma unroll
        for (int g = 0; g < 4; ++g) {
            u16 u[8];
            #pragma unroll
            for (int e = 0; e < 8; ++e) {
                float v = Ls[(g*8 + e) * 132 + t];
                acc += v * v;
                u[e] = f2bf(v);
            }
            uint4 w;
            w.x = (u32)u[0] | ((u32)u[1] << 16);
            w.y = (u32)u[2] | ((u32)u[3] << 16);
            w.z = (u32)u[4] | ((u32)u[5] << 16);
            w.w = (u32)u[6] | ((u32)u[7] << 16);
            *(uint4*)(bstrip + kc*4096 + t*32 + g*8) = w;
        }
        __syncthreads();
    }
    kinv[j] = rsqrtf(fmaxf(acc, 1e-30f));
}

// ---------------- kernel 3: per-row target logit & margins ----------------
__global__ __launch_bounds__(64)
void target_k(const float* __restrict__ Af, const u16* __restrict__ Bn,
              const float* __restrict__ kinv, const int* __restrict__ label,
              float* __restrict__ tgt, float* __restrict__ ctm,
              float* __restrict__ fin) {
    const int i = blockIdx.x, l = threadIdx.x;
    const int lab = label[i];
    const float* a = Af + i * KDIM + l * 8;
    float4 a0 = *(const float4*)a;
    float4 a1 = *(const float4*)(a + 4);
    // Bn layout: [strip][kc][col][32k]; lane l covers k = 8l..8l+7
    uint4 bv = *(const uint4*)(Bn + (size_t)(lab >> 7) * 65536
                               + (l >> 2) * 4096 + (lab & 127) * 32 + (l & 3) * 8);
    float d = a0.x * bf2f((u16)(bv.x & 0xffff)) + a0.y * bf2f((u16)(bv.x >> 16))
            + a0.z * bf2f((u16)(bv.y & 0xffff)) + a0.w * bf2f((u16)(bv.y >> 16))
            + a1.x * bf2f((u16)(bv.z & 0xffff)) + a1.y * bf2f((u16)(bv.z >> 16))
            + a1.z * bf2f((u16)(bv.w & 0xffff)) + a1.w * bf2f((u16)(bv.w >> 16));
    #pragma unroll
    for (int o = 1; o < 64; o <<= 1) d += __shfl_xor(d, o);
    if (l == 0) {
        float c = d * kinv[lab];
        c = fminf(fmaxf(c, -1.f), 1.f);
        tgt[i] = c;
        float sn = sqrtf(fmaxf(1.f - c*c, 0.f));
        float cm = c * COS_M_C - sn * SIN_M_C;
        ctm[i] = cm;
        fin[i] = (c > THRESH_C) ? cm : (c - MM_C);
    }
}

// ---------------- kernel 4: t_new scalar ----------------
__global__ __launch_bounds__(256)
void tnew_k(const float* __restrict__ tgt, const float* __restrict__ tin,
            float* __restrict__ tnw) {
    __shared__ float red[256];
    const int t = threadIdx.x;
    float s = tgt[t] + tgt[t + 256] + tgt[t + 512] + tgt[t + 768];
    red[t] = s;
    __syncthreads();
    for (int o = 128; o > 0; o >>= 1) {
        if (t < o) red[t] += red[t + o];
        __syncthreads();
    }
    if (t == 0) tnw[0] = red[0] * (0.01f / 1024.f) + 0.99f * tin[0];
}

// ---------------- kernel 5: bf16 MFMA GEMM + fused epilogue ----------------
// 128x128 tile, BK=32, 4 waves (2x2). 2-phase double-buffered LDS with
// counted vmcnt(4) + raw barriers (no compiler vmcnt(0) drain).
// XCD-chunked swizzle: all 8 M-tiles of a strip on one XCD.
__global__ __launch_bounds__(256)
void gemm_k(const u16* __restrict__ A, const u16* __restrict__ B,
            const float* __restrict__ kinv, const float* __restrict__ ctm,
            const float* __restrict__ fin, const int* __restrict__ label,
            const float* __restrict__ tnwp, float* __restrict__ out) {
    __shared__ __align__(16) u16 As[2][4096];   // 2 x 8 KB
    __shared__ __align__(16) u16 Bs[2][4096];   // 2 x 8 KB
    const int tid  = threadIdx.x;
    const int wave = tid >> 6, lane = tid & 63;

    // bijective chunked swizzle: XCD (L&7) gets contiguous work-id range;
    // within it, w&7 = M-tile (fast), w>>3 = column strip -> B reused in L2.
    const int L  = blockIdx.x;
    const int w  = (L & 7) * NSTRIP + (L >> 3);
    const int mt = w & 7;
    const int cs = w >> 3;
    const int m0 = mt * 128;
    const int j0 = cs * 128;
    const int wr = (wave >> 1) * 64;
    const int wc = (wave & 1) * 64;

    f32x4 acc[4][4] = {};

    // staging: per K-step, A tile = 128 rows x 32 k (8 KB, row-major 64B rows),
    // B tile = 8 KB linear copy of Bn's pre-tiled image.
    const int o0 = tid * 16;           // byte offset, piece 0
    const int o1 = o0 + 4096;          // piece 1
    const int rA0 = o0 >> 6, cA0 = (o0 & 63) >> 1;
    const int rA1 = o1 >> 6, cA1 = (o1 & 63) >> 1;
    const u16* gA0 = A + (m0 + rA0) * KDIM + cA0;
    const u16* gA1 = A + (m0 + rA1) * KDIM + cA1;
    const u16* gB0 = B + (size_t)cs * 65536 + (o0 >> 1);
    const u16* gB1 = gB0 + 2048;
    const int lOff0 = o0 >> 1;         // u16 offset in tile
    const int lOff1 = lOff0 + 2048;

    const int aOff = (wr + (lane & 15)) * 64 + (lane >> 4) * 16;  // bytes
    const int bOff = (wc + (lane & 15)) * 64 + (lane >> 4) * 16;

#define STAGE(b, ks)                                            \
    do {                                                        \
        gld16(gA0 + (ks) * 32, &As[b][lOff0]);                  \
        gld16(gA1 + (ks) * 32, &As[b][lOff1]);                  \
        gld16(gB0 + (ks) * 4096, &Bs[b][lOff0]);                \
        gld16(gB1 + (ks) * 4096, &Bs[b][lOff1]);                \
    } while (0)

    STAGE(0, 0);
    int cur = 0;
    #pragma unroll 2
    for (int ks = 0; ks < 16; ++ks) {
        if (ks < 15) {
            STAGE(cur ^ 1, ks + 1);
            asm volatile("s_waitcnt vmcnt(4)" ::: "memory");
        } else {
            asm volatile("s_waitcnt vmcnt(0)" ::: "memory");
        }
        __builtin_amdgcn_s_barrier();
        __builtin_amdgcn_sched_barrier(0);

        const char* aB = (const char*)As[cur] + aOff;
        const char* bB = (const char*)Bs[cur] + bOff;
        bf16x8 af[4], bfr[4];
        #pragma unroll
        for (int m = 0; m < 4; ++m)
            af[m] = *(const bf16x8*)(aB + m * 1024);
        #pragma unroll
        for (int n = 0; n < 4; ++n)
            bfr[n] = *(const bf16x8*)(bB + n * 1024);
        #pragma unroll
        for (int m = 0; m < 4; ++m)
            #pragma unroll
            for (int n = 0; n < 4; ++n)
                acc[m][n] = __builtin_amdgcn_mfma_f32_16x16x32_bf16(
                                af[m], bfr[n], acc[m][n], 0, 0, 0);

        asm volatile("s_waitcnt lgkmcnt(0)" ::: "memory");
        __builtin_amdgcn_s_barrier();
        __builtin_amdgcn_sched_barrier(0);
        cur ^= 1;
    }
#undef STAGE

    // fused epilogue
    const float tnew = *tnwp;
    const int colbase = j0 + wc + (lane & 15);
    float kv[4];
    int cols[4];
    #pragma unroll
    for (int n = 0; n < 4; ++n) {
        cols[n] = colbase + n * 16;
        kv[n] = (cols[n] < NCLS) ? kinv[cols[n]] : 0.f;
    }
    #pragma unroll
    for (int m = 0; m < 4; ++m) {
        const int rb = m0 + wr + m * 16 + (lane >> 4) * 4;
        #pragma unroll
        for (int r = 0; r < 4; ++r) {
            const int row = rb + r;
            const int lab = label[row];
            const float ct = ctm[row];
            const float fv = fin[row];
            float* orow = out + (size_t)row * NCLS;
            #pragma unroll
            for (int n = 0; n < 4; ++n) {
                float c = acc[m][n][r] * kv[n];
                c = fminf(fmaxf(c, -1.f), 1.f);
                float v = (c > ct) ? c * (tnew + c) : c;
                v = (cols[n] == lab) ? fv : v;
                if (cols[n] < NCLS)
                    orow[cols[n]] = v * S_C;
            }
        }
    }
}

extern "C" void kernel_launch(void* const* d_in, const int* in_sizes, int n_in,
                              void* d_out, int out_size, void* d_ws, size_t ws_size,
                              hipStream_t stream) {
    const float* emb = (const float*)d_in[0];
    const float* Kg  = (const float*)d_in[1];
    const float* tin = (const float*)d_in[2];
    const int*   lab = (const int*)d_in[3];
    float* out = (float*)d_out;

    char* w = (char*)d_ws;
    u16*   Bn   = (u16*)w;                         // CPAD*512*2   = 102,498,304
    u16*   Aw   = (u16*)(w + 102498304);           // 1024*512*2   =   1,048,576
    float* Af   = (float*)(w + 103546880);         // 1024*512*4   =   2,097,152
    float* kinv = (float*)(w + 105644032);         // CPAD*4       =     400,384
    float* tgt  = (float*)(w + 106044416);         // 4 KB
    float* ctmv = (float*)(w + 106048512);         // 4 KB
    float* finv = (float*)(w + 106052608);         // 4 KB
    float* tnw  = (float*)(w + 106056704);         // 4 B

    norm_emb_k<<<NROWS, 64, 0, stream>>>(emb, Af, Aw);
    transpose_norm_k<<<NSTRIP, 128, 0, stream>>>(Kg, Bn, kinv);
    target_k<<<NROWS, 64, 0, stream>>>(Af, Bn, kinv, lab, tgt, ctmv, finv);
    tnew_k<<<1, 256, 0, stream>>>(tgt, tin, tnw);
    gemm_k<<<NSTRIP * NMT, 256, 0, stream>>>(
        Aw, Bn, kinv, ctmv, finv, lab, tnw, out);
}

// Round 3
// 370.031 us; speedup vs baseline: 1.1223x; 1.1223x over previous
//
#include <hip/hip_runtime.h>

typedef unsigned short u16;
typedef unsigned int u32;
typedef __attribute__((ext_vector_type(8))) short bf16x8;
typedef __attribute__((ext_vector_type(4))) float f32x4;

#define KDIM   512
#define NROWS  1024
#define NCLS   100000
#define CPAD   100096   // 782*128
#define NSTRIP 782
#define NMT    8        // 1024/128

#define COS_M_C   0.8775825618903728f
#define SIN_M_C   0.4794255386042030f
#define THRESH_C  (-0.8775825618903728f)
#define MM_C      0.2397127693021015f
#define S_C       64.0f

__device__ __forceinline__ u16 f2bf(float f) {
    u32 x = __float_as_uint(f);
    x += 0x7fffu + ((x >> 16) & 1u);   // RNE
    return (u16)(x >> 16);
}
__device__ __forceinline__ float bf2f(u16 u) {
    return __uint_as_float(((u32)u) << 16);
}
__device__ __forceinline__ u32 pack2(float a, float b) {
    return (u32)f2bf(a) | ((u32)f2bf(b) << 16);
}
// conflict-free chunk permutation: logical (row r in 16-group, 16B-slot q)
// -> physical 16B-chunk p within the 1024B group. Each 16-lane quarter
// (fixed q, r=0..15) hits all 8 bank-quads exactly twice -> conflict-free.
__device__ __forceinline__ int phi(int r, int q) {
    return r * 4 + ((q + r + (r >> 1)) & 3);
}

__device__ __forceinline__ void gld16(const void* g, void* l) {
    __builtin_amdgcn_global_load_lds(
        (const __attribute__((address_space(1))) void*)g,
        (__attribute__((address_space(3))) void*)l, 16, 0, 0);
}

// ---------------- kernel 1: row-normalize embeddings ----------------
// Writes Af (linear f32) and Aw: bf16 GEMM staging image
// [8 m-tiles][16 kc][8 groups][64 phi-permuted 16B chunks].
__global__ __launch_bounds__(64)
void norm_emb_k(const float* __restrict__ emb, float* __restrict__ Af,
                u16* __restrict__ Aw) {
    const int i = blockIdx.x, l = threadIdx.x;
    const float* e = emb + i * KDIM;
    float4 v0 = *(const float4*)(e + l * 8);
    float4 v1 = *(const float4*)(e + l * 8 + 4);
    float s = v0.x*v0.x + v0.y*v0.y + v0.z*v0.z + v0.w*v0.w
            + v1.x*v1.x + v1.y*v1.y + v1.z*v1.z + v1.w*v1.w;
    #pragma unroll
    for (int o = 1; o < 64; o <<= 1) s += __shfl_xor(s, o);
    float inv = rsqrtf(s);
    float4 n0 = make_float4(v0.x*inv, v0.y*inv, v0.z*inv, v0.w*inv);
    float4 n1 = make_float4(v1.x*inv, v1.y*inv, v1.z*inv, v1.w*inv);
    *(float4*)(Af + i*KDIM + l*8)     = n0;
    *(float4*)(Af + i*KDIM + l*8 + 4) = n1;
    const int mt = i >> 7, g = (i >> 4) & 7, r = i & 15;
    const int kc = l >> 2, q = l & 3;
    uint4 w;
    w.x = pack2(n0.x, n0.y);
    w.y = pack2(n0.z, n0.w);
    w.z = pack2(n1.x, n1.y);
    w.w = pack2(n1.z, n1.w);
    *(uint4*)(Aw + mt*65536 + kc*4096 + g*512 + phi(r, q)*8) = w;
}

// ------- kernel 2: transpose+convert W [512][100000]f32 -> Bn bf16 in the
//         phi-permuted GEMM staging image [strip][kc][group][chunks],
//         plus per-column inverse norms -------
__global__ __launch_bounds__(128)
void transpose_norm_k(const float* __restrict__ Kg, u16* __restrict__ Bn,
                      float* __restrict__ kinv) {
    __shared__ float Ls[32 * 132];           // 32 k-rows x 128 cols, pad 132
    const int t  = threadIdx.x;
    const int jb = blockIdx.x * 128;
    const int j  = jb + t;
    u16* bstrip = Bn + (size_t)blockIdx.x * 65536;   // 16*128*32 u16
    float acc = 0.f;
    for (int kc = 0; kc < 16; ++kc) {        // chunks of 32 k
        #pragma unroll
        for (int it = 0; it < 8; ++it) {
            int fid  = it * 128 + t;
            int r    = fid >> 5;
            int c4   = (fid & 31) * 4;
            int gcol = jb + c4;
            float4 v;
            if (gcol + 3 < NCLS) {
                v = *(const float4*)(Kg + (kc*32 + r) * NCLS + gcol);
            } else {
                v.x = (gcol + 0 < NCLS) ? Kg[(kc*32 + r)*NCLS + gcol + 0] : 0.f;
                v.y = (gcol + 1 < NCLS) ? Kg[(kc*32 + r)*NCLS + gcol + 1] : 0.f;
                v.z = (gcol + 2 < NCLS) ? Kg[(kc*32 + r)*NCLS + gcol + 2] : 0.f;
                v.w = (gcol + 3 < NCLS) ? Kg[(kc*32 + r)*NCLS + gcol + 3] : 0.f;
            }
            *(float4*)(Ls + r * 132 + c4) = v;
        }
        __syncthreads();
        #pragma unroll
        for (int q = 0; q < 4; ++q) {
            u16 u[8];
            #pragma unroll
            for (int e = 0; e < 8; ++e) {
                float v = Ls[(q*8 + e) * 132 + t];
                acc += v * v;
                u[e] = f2bf(v);
            }
            uint4 w;
            w.x = (u32)u[0] | ((u32)u[1] << 16);
            w.y = (u32)u[2] | ((u32)u[3] << 16);
            w.z = (u32)u[4] | ((u32)u[5] << 16);
            w.w = (u32)u[6] | ((u32)u[7] << 16);
            *(uint4*)(bstrip + kc*4096 + (t>>4)*512 + phi(t & 15, q)*8) = w;
        }
        __syncthreads();
    }
    kinv[j] = rsqrtf(fmaxf(acc, 1e-30f));
}

// ---------------- kernel 3: per-row target logit & margins ----------------
__global__ __launch_bounds__(64)
void target_k(const float* __restrict__ Af, const u16* __restrict__ Bn,
              const float* __restrict__ kinv, const int* __restrict__ label,
              float* __restrict__ tgt, float* __restrict__ ctm,
              float* __restrict__ fin) {
    const int i = blockIdx.x, l = threadIdx.x;
    const int lab = label[i];
    const float* a = Af + i * KDIM + l * 8;
    float4 a0 = *(const float4*)a;
    float4 a1 = *(const float4*)(a + 4);
    uint4 bv = *(const uint4*)(Bn + (size_t)(lab >> 7) * 65536
               + (l >> 2) * 4096 + ((lab >> 4) & 7) * 512 + phi(lab & 15, l & 3) * 8);
    float d = a0.x * bf2f((u16)(bv.x & 0xffff)) + a0.y * bf2f((u16)(bv.x >> 16))
            + a0.z * bf2f((u16)(bv.y & 0xffff)) + a0.w * bf2f((u16)(bv.y >> 16))
            + a1.x * bf2f((u16)(bv.z & 0xffff)) + a1.y * bf2f((u16)(bv.z >> 16))
            + a1.z * bf2f((u16)(bv.w & 0xffff)) + a1.w * bf2f((u16)(bv.w >> 16));
    #pragma unroll
    for (int o = 1; o < 64; o <<= 1) d += __shfl_xor(d, o);
    if (l == 0) {
        float c = d * kinv[lab];
        c = fminf(fmaxf(c, -1.f), 1.f);
        tgt[i] = c;
        float sn = sqrtf(fmaxf(1.f - c*c, 0.f));
        float cm = c * COS_M_C - sn * SIN_M_C;
        ctm[i] = cm;
        fin[i] = (c > THRESH_C) ? cm : (c - MM_C);
    }
}

// ---------------- kernel 4: t_new scalar ----------------
__global__ __launch_bounds__(256)
void tnew_k(const float* __restrict__ tgt, const float* __restrict__ tin,
            float* __restrict__ tnw) {
    __shared__ float red[256];
    const int t = threadIdx.x;
    float s = tgt[t] + tgt[t + 256] + tgt[t + 512] + tgt[t + 768];
    red[t] = s;
    __syncthreads();
    for (int o = 128; o > 0; o >>= 1) {
        if (t < o) red[t] += red[t + o];
        __syncthreads();
    }
    if (t == 0) tnw[0] = red[0] * (0.01f / 1024.f) + 0.99f * tin[0];
}

// ---------------- kernel 5: bf16 MFMA GEMM + fused epilogue ----------------
// 128x128 tile, BK=32, 4 waves (2x2). TRUE 2-deep pipeline:
//   ds_read(cur) -> lgkmcnt(0) -> barrier -> STAGE(cur, ks+2) -> MFMA
//   -> (next iter) vmcnt(4) -> barrier
// lgkm wait can only catch >=1-iteration-old stage loads. phi-permuted
// HBM images make ds_reads bank-conflict-free with linear global_load_lds.
__global__ __launch_bounds__(256, 4)
void gemm_k(const u16* __restrict__ A, const u16* __restrict__ B,
            const float* __restrict__ kinv, const float* __restrict__ ctm,
            const float* __restrict__ fin, const int* __restrict__ label,
            const float* __restrict__ tnwp, float* __restrict__ out) {
    __shared__ __align__(16) u16 As[2][4096];   // 2 x 8 KB
    __shared__ __align__(16) u16 Bs[2][4096];   // 2 x 8 KB
    const int tid  = threadIdx.x;
    const int wave = tid >> 6, lane = tid & 63;

    // bijective XCD-chunked swizzle: all 8 M-tiles of a strip on one XCD.
    const int L  = blockIdx.x;
    const int w  = (L & 7) * NSTRIP + (L >> 3);
    const int mt = w & 7;
    const int cs = w >> 3;
    const int m0 = mt * 128;
    const int j0 = cs * 128;
    const int wr = (wave >> 1) * 64;
    const int wc = (wave & 1) * 64;

    f32x4 acc[4][4] = {};

    // linear staging: thread copies 16B at tid*16 and +4096 of each 8KB tile
    const u16* gA = A + mt * 65536 + tid * 8;
    const u16* gB = B + (size_t)cs * 65536 + tid * 8;
    const int l0 = tid * 8, l1 = tid * 8 + 2048;

    const int pphi = phi(lane & 15, lane >> 4) * 16;    // bytes
    const int aG = (wr >> 4) * 1024 + pphi;             // + m*1024
    const int bG = (wc >> 4) * 1024 + pphi;             // + n*1024

#define STAGE(b, ks) do {                               \
    gld16(gA + (ks) * 4096,        &As[b][l0]);         \
    gld16(gA + (ks) * 4096 + 2048, &As[b][l1]);         \
    gld16(gB + (ks) * 4096,        &Bs[b][l0]);         \
    gld16(gB + (ks) * 4096 + 2048, &Bs[b][l1]);         \
} while (0)

    STAGE(0, 0);
    STAGE(1, 1);
    #pragma unroll
    for (int ks = 0; ks < 16; ++ks) {
        const int cur = ks & 1;
        if (ks < 15) asm volatile("s_waitcnt vmcnt(4)" ::: "memory");
        else         asm volatile("s_waitcnt vmcnt(0)" ::: "memory");
        __builtin_amdgcn_s_barrier();           // buf[cur] ready for all waves
        __builtin_amdgcn_sched_barrier(0);

        const char* ab = (const char*)As[cur] + aG;
        const char* bb = (const char*)Bs[cur] + bG;
        bf16x8 af[4], bfr[4];
        #pragma unroll
        for (int m = 0; m < 4; ++m)
            af[m] = *(const bf16x8*)(ab + m * 1024);
        #pragma unroll
        for (int n = 0; n < 4; ++n)
            bfr[n] = *(const bf16x8*)(bb + n * 1024);

        asm volatile("s_waitcnt lgkmcnt(0)" ::: "memory");  // my reads landed
        __builtin_amdgcn_sched_barrier(0);
        __builtin_amdgcn_s_barrier();           // all waves done reading cur
        __builtin_amdgcn_sched_barrier(0);

        if (ks < 14) STAGE(cur, ks + 2);        // refill freed buffer

        __builtin_amdgcn_s_setprio(1);
        #pragma unroll
        for (int m = 0; m < 4; ++m)
            #pragma unroll
            for (int n = 0; n < 4; ++n)
                acc[m][n] = __builtin_amdgcn_mfma_f32_16x16x32_bf16(
                                af[m], bfr[n], acc[m][n], 0, 0, 0);
        __builtin_amdgcn_s_setprio(0);
    }
#undef STAGE

    // fused epilogue
    const float tnew = *tnwp;
    const int colbase = j0 + wc + (lane & 15);
    float kv[4];
    int cols[4];
    #pragma unroll
    for (int n = 0; n < 4; ++n) {
        cols[n] = colbase + n * 16;
        kv[n] = (cols[n] < NCLS) ? kinv[cols[n]] : 0.f;
    }
    #pragma unroll
    for (int m = 0; m < 4; ++m) {
        const int rb = m0 + wr + m * 16 + (lane >> 4) * 4;
        #pragma unroll
        for (int r = 0; r < 4; ++r) {
            const int row = rb + r;
            const int lab = label[row];
            const float ct = ctm[row];
            const float fv = fin[row];
            float* orow = out + (size_t)row * NCLS;
            #pragma unroll
            for (int n = 0; n < 4; ++n) {
                float c = acc[m][n][r] * kv[n];
                c = fminf(fmaxf(c, -1.f), 1.f);
                float v = (c > ct) ? c * (tnew + c) : c;
                v = (cols[n] == lab) ? fv : v;
                if (cols[n] < NCLS)
                    orow[cols[n]] = v * S_C;
            }
        }
    }
}

extern "C" void kernel_launch(void* const* d_in, const int* in_sizes, int n_in,
                              void* d_out, int out_size, void* d_ws, size_t ws_size,
                              hipStream_t stream) {
    const float* emb = (const float*)d_in[0];
    const float* Kg  = (const float*)d_in[1];
    const float* tin = (const float*)d_in[2];
    const int*   lab = (const int*)d_in[3];
    float* out = (float*)d_out;

    char* w = (char*)d_ws;
    u16*   Bn   = (u16*)w;                         // CPAD*512*2   = 102,498,304
    u16*   Aw   = (u16*)(w + 102498304);           // 1024*512*2   =   1,048,576
    float* Af   = (float*)(w + 103546880);         // 1024*512*4   =   2,097,152
    float* kinv = (float*)(w + 105644032);         // CPAD*4       =     400,384
    float* tgt  = (float*)(w + 106044416);         // 4 KB
    float* ctmv = (float*)(w + 106048512);         // 4 KB
    float* finv = (float*)(w + 106052608);         // 4 KB
    float* tnw  = (float*)(w + 106056704);         // 4 B

    norm_emb_k<<<NROWS, 64, 0, stream>>>(emb, Af, Aw);
    transpose_norm_k<<<NSTRIP, 128, 0, stream>>>(Kg, Bn, kinv);
    target_k<<<NROWS, 64, 0, stream>>>(Af, Bn, kinv, lab, tgt, ctmv, finv);
    tnew_k<<<1, 256, 0, stream>>>(tgt, tin, tnw);
    gemm_k<<<NSTRIP * NMT, 256, 0, stream>>>(
        Aw, Bn, kinv, ctmv, finv, lab, tnw, out);
}